// Round 8
// baseline (426.099 us; speedup 1.0000x reference)
//
#include <hip/hip_runtime.h>
#include <hip/hip_cooperative_groups.h>
#include <math.h>

namespace cg = cooperative_groups;

// Problem constants (reference: N=200000, D=256, 2 heads, 2 att iters)
#define NROWS 200000
#define D 256
#define F4 64          // float4 per row

// Grid: 500 blocks x 400 rows = 200000 exactly. Block = 4 waves;
// wave = 4 consecutive rows per iter, 25 iters, depth-1 prefetch (r4 structure).
#define NBLK 500
#define CHUNK 400
#define ITERS 25

// Workspace layout (floats). No atomics -> no zeroing.
#define WS_H1 0          // 512   per-head h1
#define WS_H2 512        // 512   per-head h2
#define WS_A  1024       // 2*N   a1 per row (head0 then head1)
#define WS_P1 401024     // 500*256 colsum partials
#define WS_P2 529024     // 500*512 pass partials

__device__ __forceinline__ float att_sigmoid(float s) {
    float t = s / fmaxf(fabsf(s), 1e-12f);
    return 1.0f / (1.0f + __expf(-t));
}

__device__ __forceinline__ float wave_sum(float v) {
#pragma unroll
    for (int off = 1; off < 64; off <<= 1) v += __shfl_xor(v, off);
    return v;
}

__device__ __forceinline__ float dot4(float4 a, float4 b) {
    return fmaf(a.x, b.x, fmaf(a.y, b.y, fmaf(a.z, b.z, a.w * b.w)));
}

__device__ __forceinline__ void acc4(float4& acc, float s, const float4& v) {
    acc.x = fmaf(s, v.x, acc.x);
    acc.y = fmaf(s, v.y, acc.y);
    acc.z = fmaf(s, v.z, acc.z);
    acc.w = fmaf(s, v.w, acc.w);
}

__device__ __forceinline__ float4 add4(float4 a, float4 b, float4 c, float4 d) {
    float4 s;
    s.x = (a.x + b.x) + (c.x + d.x);
    s.y = (a.y + b.y) + (c.y + d.y);
    s.z = (a.z + b.z) + (c.z + d.z);
    s.w = (a.w + b.w) + (c.w + d.w);
    return s;
}

// Shared scratch: 8 KB reduce buffer + 1 KB vbuf (phases reuse across grid.sync)
struct Smem {
    float4 sh[2][256];   // pass epilogue / colsum (uses sh[0]) / hproj red (first 256)
    float vbuf[D];
};

// ---- phase bodies (block index passed in) ----

__device__ void colsum_body(const float* __restrict__ x, float* __restrict__ part,
                            int blk, Smem& sm) {
    const int tid = threadIdx.x, lane = tid & 63, wv = tid >> 6;
    const float4* x4 = reinterpret_cast<const float4*>(x);
    const size_t base = (size_t)(blk * CHUNK + wv * 4) * F4 + lane;
    float4 cur[4], nxt[4];
#pragma unroll
    for (int j = 0; j < 4; ++j) cur[j] = x4[base + j * F4];
    float4 accA = make_float4(0.f, 0.f, 0.f, 0.f);
    float4 accB = make_float4(0.f, 0.f, 0.f, 0.f);
    for (int it = 0; it < ITERS; ++it) {
        if (it + 1 < ITERS) {
            size_t nb = base + (size_t)(it + 1) * 16 * F4;
#pragma unroll
            for (int j = 0; j < 4; ++j) nxt[j] = x4[nb + j * F4];
        }
        accA.x += cur[0].x + cur[1].x; accB.x += cur[2].x + cur[3].x;
        accA.y += cur[0].y + cur[1].y; accB.y += cur[2].y + cur[3].y;
        accA.z += cur[0].z + cur[1].z; accB.z += cur[2].z + cur[3].z;
        accA.w += cur[0].w + cur[1].w; accB.w += cur[2].w + cur[3].w;
        if (it + 1 < ITERS) {
#pragma unroll
            for (int j = 0; j < 4; ++j) cur[j] = nxt[j];
        }
    }
    accA.x += accB.x; accA.y += accB.y; accA.z += accB.z; accA.w += accB.w;
    sm.sh[0][tid] = accA;
    __syncthreads();
    if (tid < 64) {
        float4 s = add4(sm.sh[0][tid], sm.sh[0][tid + 64], sm.sh[0][tid + 128], sm.sh[0][tid + 192]);
        reinterpret_cast<float4*>(part)[blk * 64 + tid] = s;
    }
    __syncthreads();
}

__device__ void hproj_body(const float* __restrict__ W, const float* __restrict__ part,
                           int width4, int headOff4, float scale,
                           float* __restrict__ hout, int head, Smem& sm) {
    const int tid = threadIdx.x, lane = tid & 63, wv = tid >> 6;
    const float4* p4 = reinterpret_cast<const float4*>(part) + head * headOff4 + lane;
    float4 s = make_float4(0.f, 0.f, 0.f, 0.f);
#pragma unroll 5
    for (int r = wv; r < NBLK; r += 4) {
        float4 v = p4[(size_t)r * width4];
        s.x += v.x; s.y += v.y; s.z += v.z; s.w += v.w;
    }
    float4* red = &sm.sh[0][0];   // [4][64]
    red[wv * 64 + lane] = s;
    __syncthreads();
    if (tid < 64) {
        float4 v = add4(red[tid], red[64 + tid], red[128 + tid], red[192 + tid]);
        sm.vbuf[tid * 4 + 0] = v.x * scale;
        sm.vbuf[tid * 4 + 1] = v.y * scale;
        sm.vbuf[tid * 4 + 2] = v.z * scale;
        sm.vbuf[tid * 4 + 3] = v.w * scale;
    }
    __syncthreads();
    const float* Wh = W + head * D * D;
    float acc = 0.0f;
#pragma unroll 8
    for (int k = 0; k < D; ++k) acc = fmaf(sm.vbuf[k], Wh[k * D + tid], acc);
    hout[head * D + tid] = tanhf(acc);
    __syncthreads();
}

__device__ void pass1_body(const float* __restrict__ x, float* __restrict__ ws,
                           int blk, Smem& sm) {
    const float* h = ws + WS_H1;
    float* aA0 = ws + WS_A;
    float* aA1 = ws + WS_A + NROWS;
    float* part = ws + WS_P2;
    const int tid = threadIdx.x, lane = tid & 63, wv = tid >> 6;
    const int r0 = blk * CHUNK + wv * 4;
    const float4* x4 = reinterpret_cast<const float4*>(x);
    const float4 h0v = reinterpret_cast<const float4*>(h)[lane];
    const float4 h1v = reinterpret_cast<const float4*>(h + D)[lane];
    float4 acc0 = make_float4(0.f, 0.f, 0.f, 0.f);
    float4 acc1 = make_float4(0.f, 0.f, 0.f, 0.f);
    const size_t base = (size_t)r0 * F4 + lane;
    float4 cur[4], nxt[4];
#pragma unroll
    for (int j = 0; j < 4; ++j) cur[j] = x4[base + j * F4];
    for (int it = 0; it < ITERS; ++it) {
        if (it + 1 < ITERS) {
            size_t nb = base + (size_t)(it + 1) * 16 * F4;
#pragma unroll
            for (int j = 0; j < 4; ++j) nxt[j] = x4[nb + j * F4];
        }
        float d0[4], d1[4];
#pragma unroll
        for (int j = 0; j < 4; ++j) { d0[j] = dot4(cur[j], h0v); d1[j] = dot4(cur[j], h1v); }
#pragma unroll
        for (int j = 0; j < 4; ++j) { d0[j] = wave_sum(d0[j]); d1[j] = wave_sum(d1[j]); }
        float a0[4], a1[4];
#pragma unroll
        for (int j = 0; j < 4; ++j) {
            a0[j] = att_sigmoid(d0[j]);
            a1[j] = att_sigmoid(d1[j]);
            acc4(acc0, a0[j], cur[j]);
            acc4(acc1, a1[j], cur[j]);
        }
        const int rb = r0 + it * 16;
        if (lane == 0)
            *reinterpret_cast<float4*>(aA0 + rb) = make_float4(a0[0], a0[1], a0[2], a0[3]);
        else if (lane == 1)
            *reinterpret_cast<float4*>(aA1 + rb) = make_float4(a1[0], a1[1], a1[2], a1[3]);
        if (it + 1 < ITERS) {
#pragma unroll
            for (int j = 0; j < 4; ++j) cur[j] = nxt[j];
        }
    }
    sm.sh[0][tid] = acc0;
    sm.sh[1][tid] = acc1;
    __syncthreads();
    if (tid < 128) {
        int hh = tid >> 6;
        int t = tid & 63;
        const float4* s = &sm.sh[hh][0];
        float4 v = add4(s[t], s[t + 64], s[t + 128], s[t + 192]);
        reinterpret_cast<float4*>(part)[blk * 128 + tid] = v;
    }
    __syncthreads();
}

__device__ void pass2_body(const float* __restrict__ x, float* __restrict__ ws,
                           int blk, Smem& sm) {
    const float* h = ws + WS_H2;
    const float* aA0 = ws + WS_A;
    const float* aA1 = ws + WS_A + NROWS;
    float* part = ws + WS_P2;
    const int tid = threadIdx.x, lane = tid & 63, wv = tid >> 6;
    const int r0 = blk * CHUNK + wv * 4;
    const float4* x4 = reinterpret_cast<const float4*>(x);
    const float4 h0v = reinterpret_cast<const float4*>(h)[lane];
    const float4 h1v = reinterpret_cast<const float4*>(h + D)[lane];
    float4 acc0 = make_float4(0.f, 0.f, 0.f, 0.f);
    float4 acc1 = make_float4(0.f, 0.f, 0.f, 0.f);
    const size_t base = (size_t)r0 * F4 + lane;
    float4 cur[4], nxt[4];
    float4 caa0, caa1, naa0, naa1;
#pragma unroll
    for (int j = 0; j < 4; ++j) cur[j] = x4[base + j * F4];
    caa0 = *reinterpret_cast<const float4*>(aA0 + r0);
    caa1 = *reinterpret_cast<const float4*>(aA1 + r0);
    for (int it = 0; it < ITERS; ++it) {
        if (it + 1 < ITERS) {
            size_t nb = base + (size_t)(it + 1) * 16 * F4;
#pragma unroll
            for (int j = 0; j < 4; ++j) nxt[j] = x4[nb + j * F4];
            naa0 = *reinterpret_cast<const float4*>(aA0 + r0 + (it + 1) * 16);
            naa1 = *reinterpret_cast<const float4*>(aA1 + r0 + (it + 1) * 16);
        }
        float d0[4], d1[4];
#pragma unroll
        for (int j = 0; j < 4; ++j) { d0[j] = dot4(cur[j], h0v); d1[j] = dot4(cur[j], h1v); }
#pragma unroll
        for (int j = 0; j < 4; ++j) { d0[j] = wave_sum(d0[j]); d1[j] = wave_sum(d1[j]); }
        float w0[4], w1[4];
        w0[0] = att_sigmoid(caa0.x * d0[0]) * caa0.x;
        w0[1] = att_sigmoid(caa0.y * d0[1]) * caa0.y;
        w0[2] = att_sigmoid(caa0.z * d0[2]) * caa0.z;
        w0[3] = att_sigmoid(caa0.w * d0[3]) * caa0.w;
        w1[0] = att_sigmoid(caa1.x * d1[0]) * caa1.x;
        w1[1] = att_sigmoid(caa1.y * d1[1]) * caa1.y;
        w1[2] = att_sigmoid(caa1.z * d1[2]) * caa1.z;
        w1[3] = att_sigmoid(caa1.w * d1[3]) * caa1.w;
#pragma unroll
        for (int j = 0; j < 4; ++j) {
            acc4(acc0, w0[j], cur[j]);
            acc4(acc1, w1[j], cur[j]);
        }
        if (it + 1 < ITERS) {
#pragma unroll
            for (int j = 0; j < 4; ++j) cur[j] = nxt[j];
            caa0 = naa0; caa1 = naa1;
        }
    }
    sm.sh[0][tid] = acc0;
    sm.sh[1][tid] = acc1;
    __syncthreads();
    if (tid < 128) {
        int hh = tid >> 6;
        int t = tid & 63;
        const float4* s = &sm.sh[hh][0];
        float4 v = add4(s[t], s[t + 64], s[t + 128], s[t + 192]);
        reinterpret_cast<float4*>(part)[blk * 128 + tid] = v;
    }
    __syncthreads();
}

__device__ void out_reduce_body(const float* __restrict__ part, float* __restrict__ out,
                                int head, Smem& sm) {
    const int tid = threadIdx.x, lane = tid & 63, wv = tid >> 6;
    const float4* p4 = reinterpret_cast<const float4*>(part) + head * 64 + lane;
    float4 s = make_float4(0.f, 0.f, 0.f, 0.f);
#pragma unroll 5
    for (int r = wv; r < NBLK; r += 4) {
        float4 v = p4[(size_t)r * 128];
        s.x += v.x; s.y += v.y; s.z += v.z; s.w += v.w;
    }
    float4* red = &sm.sh[0][0];
    red[wv * 64 + lane] = s;
    __syncthreads();
    if (tid < 64) {
        float4 o = add4(red[tid], red[64 + tid], red[128 + tid], red[192 + tid]);
        reinterpret_cast<float4*>(out)[head * 64 + tid] = o;
    }
}

// ---- single cooperative kernel: all 6 phases, grid.sync between ----
__global__ void __launch_bounds__(256, 2) fused_kernel(const float* __restrict__ x,
                                                       const float* __restrict__ W,
                                                       float* __restrict__ out,
                                                       float* __restrict__ ws) {
    cg::grid_group grid = cg::this_grid();
    __shared__ Smem sm;
    const int b = blockIdx.x;

    colsum_body(x, ws + WS_P1, b, sm);                                  // A
    grid.sync();
    if (b < 2) hproj_body(W, ws + WS_P1, 64, 0, 1.0f / NROWS, ws + WS_H1, b, sm);   // B
    grid.sync();
    pass1_body(x, ws, b, sm);                                           // C
    grid.sync();
    if (b < 2) hproj_body(W, ws + WS_P2, 128, 64, 1.0f / NROWS, ws + WS_H2, b, sm); // D
    grid.sync();
    pass2_body(x, ws, b, sm);                                           // E
    grid.sync();
    if (b < 2) out_reduce_body(ws + WS_P2, out, b, sm);                 // F
}

extern "C" void kernel_launch(void* const* d_in, const int* in_sizes, int n_in,
                              void* d_out, int out_size, void* d_ws, size_t ws_size,
                              hipStream_t stream) {
    const float* x = (const float*)d_in[0];   // (200000, 256) f32
    const float* W = (const float*)d_in[1];   // (2, 256, 256) f32
    float* out = (float*)d_out;               // (1, 512) f32
    float* ws = (float*)d_ws;

    void* args[] = {(void*)&x, (void*)&W, (void*)&out, (void*)&ws};
    hipLaunchCooperativeKernel((void*)fused_kernel, dim3(NBLK), dim3(256),
                               args, 0, stream);
}

// Round 9
// 157.471 us; speedup vs baseline: 2.7059x; 2.7059x over previous
//
#include <hip/hip_runtime.h>
#include <math.h>

// Problem constants (reference: N=200000, D=256, 2 heads, 2 att iters)
#define NROWS 200000
#define D 256
#define F4 64          // float4 per row

// Grid: 500 blocks x 400 rows = 200000 exactly. Block = 4 waves;
// wave = 4 consecutive rows per iter, 25 iters, depth-1 prefetch.
#define NBLK 500
#define CHUNK 400
#define ITERS 25

// Workspace layout (floats). No atomics -> no zeroing.
#define WS_H1 0          // 512   per-head h1
#define WS_H2 512        // 512   per-head h2
#define WS_A  1024       // 2*N   a1 per row (head0 then head1)
#define WS_P1 401024     // 500*256 colsum partials
#define WS_P2 529024     // 500*512 pass partials
#define WS_XB 785024     // bf16 copy of x: NROWS*512 bytes (starts at float idx 785024)

__device__ __forceinline__ float att_sigmoid(float s) {
    float t = s / fmaxf(fabsf(s), 1e-12f);
    return 1.0f / (1.0f + __expf(-t));
}

__device__ __forceinline__ float wave_sum(float v) {
#pragma unroll
    for (int off = 1; off < 64; off <<= 1) v += __shfl_xor(v, off);
    return v;
}

__device__ __forceinline__ float dot4(float4 a, float4 b) {
    return fmaf(a.x, b.x, fmaf(a.y, b.y, fmaf(a.z, b.z, a.w * b.w)));
}

__device__ __forceinline__ void acc4(float4& acc, float s, const float4& v) {
    acc.x = fmaf(s, v.x, acc.x);
    acc.y = fmaf(s, v.y, acc.y);
    acc.z = fmaf(s, v.z, acc.z);
    acc.w = fmaf(s, v.w, acc.w);
}

// RNE float->bf16, pack two into one u32 (a = low short / even col)
__device__ __forceinline__ unsigned int packbf2(float a, float b) {
    unsigned int ua = __float_as_uint(a);
    unsigned int ub = __float_as_uint(b);
    ua = (ua + 0x7FFFu + ((ua >> 16) & 1u)) >> 16;
    ub = (ub + 0x7FFFu + ((ub >> 16) & 1u)) >> 16;
    return ua | (ub << 16);
}

__device__ __forceinline__ void unpack8(uint4 q, float* f) {
    f[0] = __uint_as_float(q.x << 16); f[1] = __uint_as_float(q.x & 0xFFFF0000u);
    f[2] = __uint_as_float(q.y << 16); f[3] = __uint_as_float(q.y & 0xFFFF0000u);
    f[4] = __uint_as_float(q.z << 16); f[5] = __uint_as_float(q.z & 0xFFFF0000u);
    f[6] = __uint_as_float(q.w << 16); f[7] = __uint_as_float(q.w & 0xFFFF0000u);
}

// ---- A': colsum partials + write bf16 copy of x ----
__global__ void __launch_bounds__(256) colsum_cast_kernel(const float* __restrict__ x,
                                                          float* __restrict__ part,
                                                          uint2* __restrict__ xb2) {
    const int tid = threadIdx.x, lane = tid & 63, wv = tid >> 6;
    const float4* x4 = reinterpret_cast<const float4*>(x);
    const int r0 = blockIdx.x * CHUNK + wv * 4;
    const size_t base = (size_t)r0 * F4 + lane;
    float4 cur[4], nxt[4];
#pragma unroll
    for (int j = 0; j < 4; ++j) cur[j] = x4[base + j * F4];
    float4 accA = make_float4(0.f, 0.f, 0.f, 0.f);
    float4 accB = make_float4(0.f, 0.f, 0.f, 0.f);
    for (int it = 0; it < ITERS; ++it) {
        if (it + 1 < ITERS) {
            size_t nb = base + (size_t)(it + 1) * 16 * F4;
#pragma unroll
            for (int j = 0; j < 4; ++j) nxt[j] = x4[nb + j * F4];
        }
        accA.x += cur[0].x + cur[1].x; accB.x += cur[2].x + cur[3].x;
        accA.y += cur[0].y + cur[1].y; accB.y += cur[2].y + cur[3].y;
        accA.z += cur[0].z + cur[1].z; accB.z += cur[2].z + cur[3].z;
        accA.w += cur[0].w + cur[1].w; accB.w += cur[2].w + cur[3].w;
        const int rb = r0 + it * 16;
#pragma unroll
        for (int j = 0; j < 4; ++j) {
            xb2[(size_t)(rb + j) * 64 + lane] =
                make_uint2(packbf2(cur[j].x, cur[j].y), packbf2(cur[j].z, cur[j].w));
        }
        if (it + 1 < ITERS) {
#pragma unroll
            for (int j = 0; j < 4; ++j) cur[j] = nxt[j];
        }
    }
    accA.x += accB.x; accA.y += accB.y; accA.z += accB.z; accA.w += accB.w;
    __shared__ float4 sh[256];
    sh[tid] = accA;
    __syncthreads();
    if (tid < 64) {
        float4 a = sh[tid], b = sh[tid + 64], c = sh[tid + 128], d = sh[tid + 192];
        float4 s;
        s.x = (a.x + b.x) + (c.x + d.x);
        s.y = (a.y + b.y) + (c.y + d.y);
        s.z = (a.z + b.z) + (c.z + d.z);
        s.w = (a.w + b.w) + (c.w + d.w);
        reinterpret_cast<float4*>(part)[blockIdx.x * 64 + tid] = s;
    }
}

// ---- fused: reduce NBLK partial rows -> v, then h = tanh((v*scale) @ W) ----
__global__ void __launch_bounds__(256) hproj_fused(const float* __restrict__ W,
                                                   const float* __restrict__ part,
                                                   int width4, int headOff4, float scale,
                                                   float* __restrict__ hout) {
    const int head = blockIdx.x;
    const int tid = threadIdx.x, lane = tid & 63, wv = tid >> 6;
    const float4* p4 = reinterpret_cast<const float4*>(part) + head * headOff4 + lane;
    float4 s = make_float4(0.f, 0.f, 0.f, 0.f);
#pragma unroll 5
    for (int r = wv; r < NBLK; r += 4) {
        float4 v = p4[(size_t)r * width4];
        s.x += v.x; s.y += v.y; s.z += v.z; s.w += v.w;
    }
    __shared__ float4 red[4][64];
    __shared__ float vbuf[D];
    red[wv][lane] = s;
    __syncthreads();
    if (tid < 64) {
        float4 a = red[0][tid], b = red[1][tid], c = red[2][tid], d = red[3][tid];
        vbuf[tid * 4 + 0] = ((a.x + b.x) + (c.x + d.x)) * scale;
        vbuf[tid * 4 + 1] = ((a.y + b.y) + (c.y + d.y)) * scale;
        vbuf[tid * 4 + 2] = ((a.z + b.z) + (c.z + d.z)) * scale;
        vbuf[tid * 4 + 3] = ((a.w + b.w) + (c.w + d.w)) * scale;
    }
    __syncthreads();
    const float* Wh = W + head * D * D;
    float acc = 0.0f;
#pragma unroll 8
    for (int k = 0; k < D; ++k) acc = fmaf(vbuf[k], Wh[k * D + tid], acc);
    hout[head * D + tid] = tanhf(acc);
}

// ---- C': pass1 on bf16 copy ----
// Wave covers 4 rows/iter. Lane: hi=lane>>5 selects row parity, chunk=lane&31 -> cols chunk*8..+7.
// j=0 -> rows rb+hi, j=1 -> rows rb+2+hi. 16B uint4 load = 8 bf16.
__global__ void __launch_bounds__(256) pass1_bf16_kernel(const uint4* __restrict__ xb,
                                                         float* __restrict__ ws) {
    const float* h = ws + WS_H1;
    float* aA0 = ws + WS_A;
    float* aA1 = ws + WS_A + NROWS;
    float* part = ws + WS_P2;
    const int tid = threadIdx.x, lane = tid & 63, wv = tid >> 6;
    const int hi = lane >> 5, chunk = lane & 31, c0 = chunk * 8;
    const int r0 = blockIdx.x * CHUNK + wv * 4;
    float hh0[8], hh1[8];
#pragma unroll
    for (int k = 0; k < 8; ++k) { hh0[k] = h[c0 + k]; hh1[k] = h[D + c0 + k]; }
    float acc0[8], acc1[8];
#pragma unroll
    for (int k = 0; k < 8; ++k) { acc0[k] = 0.f; acc1[k] = 0.f; }
    const size_t base = (size_t)r0 * 32;   // 32 uint4 per row
    uint4 cur0 = xb[base + lane];
    uint4 cur1 = xb[base + 64 + lane];
    for (int it = 0; it < ITERS; ++it) {
        uint4 nxt0, nxt1;
        if (it + 1 < ITERS) {
            const size_t nb = base + (size_t)(it + 1) * 512;
            nxt0 = xb[nb + lane];
            nxt1 = xb[nb + 64 + lane];
        }
        float f0[8], f1[8];
        unpack8(cur0, f0);
        unpack8(cur1, f1);
        float d00 = 0.f, d01 = 0.f, d10 = 0.f, d11 = 0.f;  // d{head}{j}
#pragma unroll
        for (int k = 0; k < 8; ++k) {
            d00 = fmaf(f0[k], hh0[k], d00); d10 = fmaf(f0[k], hh1[k], d10);
            d01 = fmaf(f1[k], hh0[k], d01); d11 = fmaf(f1[k], hh1[k], d11);
        }
#pragma unroll
        for (int off = 1; off < 32; off <<= 1) {
            d00 += __shfl_xor(d00, off); d01 += __shfl_xor(d01, off);
            d10 += __shfl_xor(d10, off); d11 += __shfl_xor(d11, off);
        }
        float a00 = att_sigmoid(d00), a01 = att_sigmoid(d01);
        float a10 = att_sigmoid(d10), a11 = att_sigmoid(d11);
        const int rb = r0 + it * 16;
        if (chunk == 0) {
            aA0[rb + hi] = a00; aA0[rb + 2 + hi] = a01;
            aA1[rb + hi] = a10; aA1[rb + 2 + hi] = a11;
        }
#pragma unroll
        for (int k = 0; k < 8; ++k) {
            acc0[k] = fmaf(a00, f0[k], acc0[k]); acc0[k] = fmaf(a01, f1[k], acc0[k]);
            acc1[k] = fmaf(a10, f0[k], acc1[k]); acc1[k] = fmaf(a11, f1[k], acc1[k]);
        }
        cur0 = nxt0; cur1 = nxt1;
    }
    __shared__ float lds[256][17];
#pragma unroll
    for (int k = 0; k < 8; ++k) { lds[tid][k] = acc0[k]; lds[tid][8 + k] = acc1[k]; }
    __syncthreads();
    float s0 = 0.f, s1 = 0.f;
#pragma unroll
    for (int g = 0; g < 8; ++g) {
        s0 += lds[g * 32 + (tid >> 3)][tid & 7];
        s1 += lds[g * 32 + (tid >> 3)][8 + (tid & 7)];
    }
    part[blockIdx.x * 512 + tid] = s0;
    part[blockIdx.x * 512 + 256 + tid] = s1;
}

// ---- E': pass2 on bf16 copy ----
__global__ void __launch_bounds__(256) pass2_bf16_kernel(const uint4* __restrict__ xb,
                                                         float* __restrict__ ws) {
    const float* h = ws + WS_H2;
    const float* aA0 = ws + WS_A;
    const float* aA1 = ws + WS_A + NROWS;
    float* part = ws + WS_P2;
    const int tid = threadIdx.x, lane = tid & 63, wv = tid >> 6;
    const int hi = lane >> 5, chunk = lane & 31, c0 = chunk * 8;
    const int r0 = blockIdx.x * CHUNK + wv * 4;
    float hh0[8], hh1[8];
#pragma unroll
    for (int k = 0; k < 8; ++k) { hh0[k] = h[c0 + k]; hh1[k] = h[D + c0 + k]; }
    float acc0[8], acc1[8];
#pragma unroll
    for (int k = 0; k < 8; ++k) { acc0[k] = 0.f; acc1[k] = 0.f; }
    const size_t base = (size_t)r0 * 32;
    uint4 cur0 = xb[base + lane];
    uint4 cur1 = xb[base + 64 + lane];
    for (int it = 0; it < ITERS; ++it) {
        uint4 nxt0, nxt1;
        if (it + 1 < ITERS) {
            const size_t nb = base + (size_t)(it + 1) * 512;
            nxt0 = xb[nb + lane];
            nxt1 = xb[nb + 64 + lane];
        }
        const int rb = r0 + it * 16;
        float aa00 = aA0[rb + hi], aa01 = aA0[rb + 2 + hi];
        float aa10 = aA1[rb + hi], aa11 = aA1[rb + 2 + hi];
        float f0[8], f1[8];
        unpack8(cur0, f0);
        unpack8(cur1, f1);
        float d00 = 0.f, d01 = 0.f, d10 = 0.f, d11 = 0.f;
#pragma unroll
        for (int k = 0; k < 8; ++k) {
            d00 = fmaf(f0[k], hh0[k], d00); d10 = fmaf(f0[k], hh1[k], d10);
            d01 = fmaf(f1[k], hh0[k], d01); d11 = fmaf(f1[k], hh1[k], d11);
        }
#pragma unroll
        for (int off = 1; off < 32; off <<= 1) {
            d00 += __shfl_xor(d00, off); d01 += __shfl_xor(d01, off);
            d10 += __shfl_xor(d10, off); d11 += __shfl_xor(d11, off);
        }
        float w00 = att_sigmoid(aa00 * d00) * aa00;
        float w01 = att_sigmoid(aa01 * d01) * aa01;
        float w10 = att_sigmoid(aa10 * d10) * aa10;
        float w11 = att_sigmoid(aa11 * d11) * aa11;
#pragma unroll
        for (int k = 0; k < 8; ++k) {
            acc0[k] = fmaf(w00, f0[k], acc0[k]); acc0[k] = fmaf(w01, f1[k], acc0[k]);
            acc1[k] = fmaf(w10, f0[k], acc1[k]); acc1[k] = fmaf(w11, f1[k], acc1[k]);
        }
        cur0 = nxt0; cur1 = nxt1;
    }
    __shared__ float lds[256][17];
#pragma unroll
    for (int k = 0; k < 8; ++k) { lds[tid][k] = acc0[k]; lds[tid][8 + k] = acc1[k]; }
    __syncthreads();
    float s0 = 0.f, s1 = 0.f;
#pragma unroll
    for (int g = 0; g < 8; ++g) {
        s0 += lds[g * 32 + (tid >> 3)][tid & 7];
        s1 += lds[g * 32 + (tid >> 3)][8 + (tid & 7)];
    }
    part[blockIdx.x * 512 + tid] = s0;
    part[blockIdx.x * 512 + 256 + tid] = s1;
}

// ================= fallback (exact r4 fp32 path) =================
__global__ void __launch_bounds__(256) colsum_kernel(const float* __restrict__ x,
                                                     float* __restrict__ part) {
    const int tid = threadIdx.x, lane = tid & 63, wv = tid >> 6;
    const float4* x4 = reinterpret_cast<const float4*>(x);
    const size_t base = (size_t)(blockIdx.x * CHUNK + wv * 4) * F4 + lane;
    float4 cur[4], nxt[4];
#pragma unroll
    for (int j = 0; j < 4; ++j) cur[j] = x4[base + j * F4];
    float4 accA = make_float4(0.f, 0.f, 0.f, 0.f);
    float4 accB = make_float4(0.f, 0.f, 0.f, 0.f);
    for (int it = 0; it < ITERS; ++it) {
        if (it + 1 < ITERS) {
            size_t nb = base + (size_t)(it + 1) * 16 * F4;
#pragma unroll
            for (int j = 0; j < 4; ++j) nxt[j] = x4[nb + j * F4];
        }
        accA.x += cur[0].x + cur[1].x; accB.x += cur[2].x + cur[3].x;
        accA.y += cur[0].y + cur[1].y; accB.y += cur[2].y + cur[3].y;
        accA.z += cur[0].z + cur[1].z; accB.z += cur[2].z + cur[3].z;
        accA.w += cur[0].w + cur[1].w; accB.w += cur[2].w + cur[3].w;
        if (it + 1 < ITERS) {
#pragma unroll
            for (int j = 0; j < 4; ++j) cur[j] = nxt[j];
        }
    }
    accA.x += accB.x; accA.y += accB.y; accA.z += accB.z; accA.w += accB.w;
    __shared__ float4 sh[256];
    sh[tid] = accA;
    __syncthreads();
    if (tid < 64) {
        float4 a = sh[tid], b = sh[tid + 64], c = sh[tid + 128], d = sh[tid + 192];
        float4 s;
        s.x = (a.x + b.x) + (c.x + d.x);
        s.y = (a.y + b.y) + (c.y + d.y);
        s.z = (a.z + b.z) + (c.z + d.z);
        s.w = (a.w + b.w) + (c.w + d.w);
        reinterpret_cast<float4*>(part)[blockIdx.x * 64 + tid] = s;
    }
}

__global__ void __launch_bounds__(256) pass1_kernel(const float* __restrict__ x,
                                                    float* __restrict__ ws) {
    const float* h = ws + WS_H1;
    float* aA0 = ws + WS_A;
    float* aA1 = ws + WS_A + NROWS;
    float* part = ws + WS_P2;
    const int tid = threadIdx.x, lane = tid & 63, wv = tid >> 6;
    const int r0 = blockIdx.x * CHUNK + wv * 4;
    const float4* x4 = reinterpret_cast<const float4*>(x);
    const float4 h0v = reinterpret_cast<const float4*>(h)[lane];
    const float4 h1v = reinterpret_cast<const float4*>(h + D)[lane];
    float4 acc0 = make_float4(0.f, 0.f, 0.f, 0.f);
    float4 acc1 = make_float4(0.f, 0.f, 0.f, 0.f);
    const size_t base = (size_t)r0 * F4 + lane;
    float4 cur[4], nxt[4];
#pragma unroll
    for (int j = 0; j < 4; ++j) cur[j] = x4[base + j * F4];
    for (int it = 0; it < ITERS; ++it) {
        if (it + 1 < ITERS) {
            size_t nb = base + (size_t)(it + 1) * 16 * F4;
#pragma unroll
            for (int j = 0; j < 4; ++j) nxt[j] = x4[nb + j * F4];
        }
        float d0[4], d1[4];
#pragma unroll
        for (int j = 0; j < 4; ++j) { d0[j] = dot4(cur[j], h0v); d1[j] = dot4(cur[j], h1v); }
#pragma unroll
        for (int j = 0; j < 4; ++j) { d0[j] = wave_sum(d0[j]); d1[j] = wave_sum(d1[j]); }
        float a0[4], a1[4];
#pragma unroll
        for (int j = 0; j < 4; ++j) {
            a0[j] = att_sigmoid(d0[j]);
            a1[j] = att_sigmoid(d1[j]);
            acc4(acc0, a0[j], cur[j]);
            acc4(acc1, a1[j], cur[j]);
        }
        const int rb = r0 + it * 16;
        if (lane == 0)
            *reinterpret_cast<float4*>(aA0 + rb) = make_float4(a0[0], a0[1], a0[2], a0[3]);
        else if (lane == 1)
            *reinterpret_cast<float4*>(aA1 + rb) = make_float4(a1[0], a1[1], a1[2], a1[3]);
        if (it + 1 < ITERS) {
#pragma unroll
            for (int j = 0; j < 4; ++j) cur[j] = nxt[j];
        }
    }
    __shared__ float4 sh[2][256];
    sh[0][tid] = acc0;
    sh[1][tid] = acc1;
    __syncthreads();
    if (tid < 128) {
        int hh = tid >> 6;
        int t = tid & 63;
        float4 a = sh[hh][t], b = sh[hh][t + 64], c = sh[hh][t + 128], d = sh[hh][t + 192];
        float4 s;
        s.x = (a.x + b.x) + (c.x + d.x);
        s.y = (a.y + b.y) + (c.y + d.y);
        s.z = (a.z + b.z) + (c.z + d.z);
        s.w = (a.w + b.w) + (c.w + d.w);
        reinterpret_cast<float4*>(part)[blockIdx.x * 128 + tid] = s;
    }
}

__global__ void __launch_bounds__(256) pass2_kernel(const float* __restrict__ x,
                                                    float* __restrict__ ws) {
    const float* h = ws + WS_H2;
    const float* aA0 = ws + WS_A;
    const float* aA1 = ws + WS_A + NROWS;
    float* part = ws + WS_P2;
    const int tid = threadIdx.x, lane = tid & 63, wv = tid >> 6;
    const int r0 = blockIdx.x * CHUNK + wv * 4;
    const float4* x4 = reinterpret_cast<const float4*>(x);
    const float4 h0v = reinterpret_cast<const float4*>(h)[lane];
    const float4 h1v = reinterpret_cast<const float4*>(h + D)[lane];
    float4 acc0 = make_float4(0.f, 0.f, 0.f, 0.f);
    float4 acc1 = make_float4(0.f, 0.f, 0.f, 0.f);
    const size_t base = (size_t)r0 * F4 + lane;
    float4 cur[4], nxt[4];
    float4 caa0, caa1, naa0, naa1;
#pragma unroll
    for (int j = 0; j < 4; ++j) cur[j] = x4[base + j * F4];
    caa0 = *reinterpret_cast<const float4*>(aA0 + r0);
    caa1 = *reinterpret_cast<const float4*>(aA1 + r0);
    for (int it = 0; it < ITERS; ++it) {
        if (it + 1 < ITERS) {
            size_t nb = base + (size_t)(it + 1) * 16 * F4;
#pragma unroll
            for (int j = 0; j < 4; ++j) nxt[j] = x4[nb + j * F4];
            naa0 = *reinterpret_cast<const float4*>(aA0 + r0 + (it + 1) * 16);
            naa1 = *reinterpret_cast<const float4*>(aA1 + r0 + (it + 1) * 16);
        }
        float d0[4], d1[4];
#pragma unroll
        for (int j = 0; j < 4; ++j) { d0[j] = dot4(cur[j], h0v); d1[j] = dot4(cur[j], h1v); }
#pragma unroll
        for (int j = 0; j < 4; ++j) { d0[j] = wave_sum(d0[j]); d1[j] = wave_sum(d1[j]); }
        float w0[4], w1[4];
        w0[0] = att_sigmoid(caa0.x * d0[0]) * caa0.x;
        w0[1] = att_sigmoid(caa0.y * d0[1]) * caa0.y;
        w0[2] = att_sigmoid(caa0.z * d0[2]) * caa0.z;
        w0[3] = att_sigmoid(caa0.w * d0[3]) * caa0.w;
        w1[0] = att_sigmoid(caa1.x * d1[0]) * caa1.x;
        w1[1] = att_sigmoid(caa1.y * d1[1]) * caa1.y;
        w1[2] = att_sigmoid(caa1.z * d1[2]) * caa1.z;
        w1[3] = att_sigmoid(caa1.w * d1[3]) * caa1.w;
#pragma unroll
        for (int j = 0; j < 4; ++j) {
            acc4(acc0, w0[j], cur[j]);
            acc4(acc1, w1[j], cur[j]);
        }
        if (it + 1 < ITERS) {
#pragma unroll
            for (int j = 0; j < 4; ++j) cur[j] = nxt[j];
            caa0 = naa0; caa1 = naa1;
        }
    }
    __shared__ float4 sh[2][256];
    sh[0][tid] = acc0;
    sh[1][tid] = acc1;
    __syncthreads();
    if (tid < 128) {
        int hh = tid >> 6;
        int t = tid & 63;
        float4 a = sh[hh][t], b = sh[hh][t + 64], c = sh[hh][t + 128], d = sh[hh][t + 192];
        float4 s;
        s.x = (a.x + b.x) + (c.x + d.x);
        s.y = (a.y + b.y) + (c.y + d.y);
        s.z = (a.z + b.z) + (c.z + d.z);
        s.w = (a.w + b.w) + (c.w + d.w);
        reinterpret_cast<float4*>(part)[blockIdx.x * 128 + tid] = s;
    }
}

// ---- final: out[head*256+c] = sum over NBLK partial rows (direct store) ----
__global__ void __launch_bounds__(256) out_reduce(const float* __restrict__ part,
                                                  float* __restrict__ out) {
    const int head = blockIdx.x;
    const int tid = threadIdx.x, lane = tid & 63, wv = tid >> 6;
    const float4* p4 = reinterpret_cast<const float4*>(part) + head * 64 + lane;
    float4 s = make_float4(0.f, 0.f, 0.f, 0.f);
#pragma unroll 5
    for (int r = wv; r < NBLK; r += 4) {
        float4 v = p4[(size_t)r * 128];
        s.x += v.x; s.y += v.y; s.z += v.z; s.w += v.w;
    }
    __shared__ float4 red[4][64];
    red[wv][lane] = s;
    __syncthreads();
    if (tid < 64) {
        float4 a = red[0][tid], b = red[1][tid], c = red[2][tid], d = red[3][tid];
        float4 o;
        o.x = (a.x + b.x) + (c.x + d.x);
        o.y = (a.y + b.y) + (c.y + d.y);
        o.z = (a.z + b.z) + (c.z + d.z);
        o.w = (a.w + b.w) + (c.w + d.w);
        reinterpret_cast<float4*>(out)[head * 64 + tid] = o;
    }
}

extern "C" void kernel_launch(void* const* d_in, const int* in_sizes, int n_in,
                              void* d_out, int out_size, void* d_ws, size_t ws_size,
                              hipStream_t stream) {
    const float* x = (const float*)d_in[0];   // (200000, 256) f32
    const float* W = (const float*)d_in[1];   // (2, 256, 256) f32
    float* out = (float*)d_out;               // (1, 512) f32
    float* ws = (float*)d_ws;

    const size_t need = (size_t)WS_XB * 4 + (size_t)NROWS * 512;  // ~105.5 MB
    if (ws_size >= need) {
        uint2* xb2 = reinterpret_cast<uint2*>(ws + WS_XB);
        const uint4* xb4 = reinterpret_cast<const uint4*>(ws + WS_XB);
        colsum_cast_kernel<<<dim3(NBLK), dim3(256), 0, stream>>>(x, ws + WS_P1, xb2);
        hproj_fused<<<dim3(2), dim3(256), 0, stream>>>(W, ws + WS_P1, 64, 0, 1.0f / NROWS, ws + WS_H1);
        pass1_bf16_kernel<<<dim3(NBLK), dim3(256), 0, stream>>>(xb4, ws);
        hproj_fused<<<dim3(2), dim3(256), 0, stream>>>(W, ws + WS_P2, 128, 64, 1.0f / NROWS, ws + WS_H2);
        pass2_bf16_kernel<<<dim3(NBLK), dim3(256), 0, stream>>>(xb4, ws);
        out_reduce<<<dim3(2), dim3(256), 0, stream>>>(ws + WS_P2, out);
    } else {
        colsum_kernel<<<dim3(NBLK), dim3(256), 0, stream>>>(x, ws + WS_P1);
        hproj_fused<<<dim3(2), dim3(256), 0, stream>>>(W, ws + WS_P1, 64, 0, 1.0f / NROWS, ws + WS_H1);
        pass1_kernel<<<dim3(NBLK), dim3(256), 0, stream>>>(x, ws);
        hproj_fused<<<dim3(2), dim3(256), 0, stream>>>(W, ws + WS_P2, 128, 64, 1.0f / NROWS, ws + WS_H2);
        pass2_kernel<<<dim3(NBLK), dim3(256), 0, stream>>>(x, ws);
        out_reduce<<<dim3(2), dim3(256), 0, stream>>>(ws + WS_P2, out);
    }
}